// Round 1
// baseline (241.532 us; speedup 1.0000x reference)
//
#include <hip/hip_runtime.h>

// SNN forward scan: B=64, N=1024, T=512. Row = (b*N+n), x[row*512 + t].
//
// R8: non-temporal output stores. Evidence: FETCH_SIZE=65.6MB < 134MB input
// with ZERO intra-kernel reuse -> ~half the input is LLC-resident across
// bench iterations; the other half is evicted by our own 134-MB output
// write stream allocating in the 256-MB Infinity Cache. Marking the spike
// stores non-temporal (no-allocate) keeps the full input LLC-resident, so
// HBM sees a near-pure write stream: fewer read/write turnarounds and
// row-buffer conflicts for the 256-B@2-KB-stride pattern.
// Predicted: FETCH_SIZE < 30MB, WRITE_SIZE unchanged, dur 94 -> 60-75 us.
//
// Structure unchanged from R7 (verified bit-exact): CHUNK=64 -> each
// load/store instr covers 4 rows x 256 B CONTIGUOUS. LDS: inbuf x2 +
// outbuf x1 = 49.9 KB (3 blocks/CU). Two phases per chunk: A) store drains
// chunk k-1 from outbuf, compute computes chunk k into registers;
// lgkm-barrier; B) compute writes spikes to outbuf. STRIDE=65 (odd) + b32
// LDS ops -> zero bank conflicts.
//
// Numerics: BIT-EXACT vs float32 NumPy reference (0/1 threshold output —
// one ulp flip cascades). __fmul_rn/__fadd_rn + contract(off).
#pragma clang fp contract(off)

#define ROWS    64                    // rows per block (1 compute wave)
#define T_LEN   512
#define CHUNK   64                    // timesteps per tile (256 B/row contiguous)
#define NCHUNK  (T_LEN / CHUNK)       // 8
#define STRIDE  (CHUNK + 1)           // 65: odd -> conflict-free b32 LDS
#define NV      16                    // float4 per io-lane per chunk
#define NPARAM  1024

typedef float f4_nt __attribute__((ext_vector_type(4)));

// lgkmcnt(0)-only barrier: LDS visibility without the vmcnt(0) drain.
#define BARRIER() asm volatile("s_waitcnt lgkmcnt(0)\n\ts_barrier" ::: "memory")

__global__ __launch_bounds__(192) void snn_fwd(
    const float* __restrict__ x,
    const float* __restrict__ beta,
    const float* __restrict__ p,
    const float* __restrict__ bparam,
    float* __restrict__ out)
{
    __shared__ float inbuf[2][ROWS * STRIDE];  // 2 x 16,640 B
    __shared__ float outbuf[ROWS * STRIDE];    //     16,640 B  (49.9 KB total)

    const int tid     = threadIdx.x;
    const int wid     = tid >> 6;       // 0=compute, 1=load, 2=store
    const int lane    = tid & 63;
    const int rowBase = blockIdx.x * ROWS;

    const float4* __restrict__ xv = (const float4*)x;  // row stride 128 float4
    float4* __restrict__ ov       = (float4*)out;

    // io mapping: lane = r4*16 + t16. One instr: rows {r4+4*it}, 16 float4
    // (=256 B) contiguous per row. Chunk k adds k*NV float4.
    const int t16 = lane & 15;
    const int r4  = lane >> 4;
    const int gq  = (rowBase + r4) * (T_LEN / 4) + t16;  // float4 units
    const int lf  = r4 * STRIDE + t16 * 4;               // float units

    // compute state
    float mem = 0.0f, refac = 2.0f, a = 0.0f, vth = 1.0f, ps = 0.0f;
    float beta_c = 0.f, p_c = 0.f, b_c = 0.f;
    const int cb = lane * STRIDE;  // compute lane's LDS row

    if (wid == 0) {
        const int n = (rowBase + lane) & (NPARAM - 1);
        beta_c = fminf(fmaxf(beta[n], 0.001f), 0.999f);
        p_c    = fminf(fabsf(p[n]), 0.999f);
        b_c    = fminf(fmaxf(fabsf(bparam[n]), 0.001f), 1.0f);
    }

    auto step = [&](float xt) -> float {
        refac = (ps > 0.0f) ? 0.0f : refac;           // spike-triggered reset
        const float ic = (refac < 2.0f) ? 0.0f : xt;  // refractory input mask
        refac += 1.0f;
        const float nm   = __fadd_rn(__fmul_rn(mem, beta_c), ic);  // integrate
        const float diff = __fsub_rn(nm, vth);
        const float s    = (diff > 0.0f) ? 1.0f : 0.0f;
        mem = (diff > 0.0f) ? 0.0f : nm;              // reset-to-zero on spike
        a   = __fadd_rn(__fmul_rn(p_c, a), s);        // adaptation
        vth = __fadd_rn(1.0f, __fmul_rn(b_c, a));     // adaptive threshold
        ps  = s;
        return s;
    };

    float4 ld[NV];  // load wave's register pipeline (one chunk ahead)

    auto loadChunk = [&](int k) {
        const int base = gq + k * NV;
        #pragma unroll
        for (int it = 0; it < NV; ++it)
            ld[it] = xv[base + it * 4 * (T_LEN / 4)];  // +4 rows per it
    };
    auto stage = [&](int buf) {   // b32 scatter into [row][65] layout
        #pragma unroll
        for (int it = 0; it < NV; ++it) {
            const int o = lf + it * 4 * STRIDE;
            inbuf[buf][o + 0] = ld[it].x;
            inbuf[buf][o + 1] = ld[it].y;
            inbuf[buf][o + 2] = ld[it].z;
            inbuf[buf][o + 3] = ld[it].w;
        }
    };
    auto drain = [&](int k) {     // outbuf -> global, 256 B/row contiguous, NT
        const int base = gq + k * NV;
        #pragma unroll
        for (int it = 0; it < NV; ++it) {
            const int o = lf + it * 4 * STRIDE;
            float4 sv;
            sv.x = outbuf[o + 0];
            sv.y = outbuf[o + 1];
            sv.z = outbuf[o + 2];
            sv.w = outbuf[o + 3];
            // non-temporal: bypass LLC allocation so the input stays resident
            __builtin_nontemporal_store(
                *reinterpret_cast<f4_nt*>(&sv),
                reinterpret_cast<f4_nt*>(&ov[base + it * 4 * (T_LEN / 4)]));
        }
    };

    // preamble: chunk 0 staged; chunk 1 in regs (in flight across barrier)
    if (wid == 1) {
        loadChunk(0);
        stage(0);
        loadChunk(1);
    }
    BARRIER();

    #pragma unroll 1
    for (int k = 0; k < NCHUNK; ++k) {
        const int cur = k & 1;
        float sv[CHUNK];
        // ---- phase A ----
        if (wid == 0) {
            // compute chunk k from inbuf[cur] into registers
            #pragma unroll
            for (int t = 0; t < CHUNK; ++t)
                sv[t] = step(inbuf[cur][cb + t]);
        } else if (wid == 1) {
            if (k + 1 < NCHUNK) stage(cur ^ 1);     // regs loaded one chunk ago
            if (k + 2 < NCHUNK) loadChunk(k + 2);   // refill register pipeline
        } else {
            if (k > 0) drain(k - 1);                // spikes written in k-1's B
        }
        BARRIER();  // store's outbuf reads done; inbuf[cur^1] staged
        // ---- phase B ----
        if (wid == 0) {
            #pragma unroll
            for (int t = 0; t < CHUNK; ++t)
                outbuf[cb + t] = sv[t];
        }
        BARRIER();  // outbuf[k] visible to store wave next iteration
    }
    if (wid == 2) drain(NCHUNK - 1);
}

extern "C" void kernel_launch(void* const* d_in, const int* in_sizes, int n_in,
                              void* d_out, int out_size, void* d_ws, size_t ws_size,
                              hipStream_t stream) {
    const float* x    = (const float*)d_in[0];
    const float* beta = (const float*)d_in[1];
    const float* p    = (const float*)d_in[2];
    const float* b    = (const float*)d_in[3];
    float* out        = (float*)d_out;

    const int BN = 64 * 1024;  // rows
    snn_fwd<<<dim3(BN / ROWS), dim3(192), 0, stream>>>(x, beta, p, b, out);
}